// Round 7
// baseline (74.479 us; speedup 1.0000x reference)
//
#include <hip/hip_runtime.h>
#include <stdint.h>

#define NN 200000
#define DEG 32
#define BB 16384
#define DD 128
#define HH 128
#define BM 16

typedef __attribute__((ext_vector_type(8))) short bf16x8;
typedef __attribute__((ext_vector_type(4))) float f32x4;

struct Keys { unsigned a[5][2]; unsigned l[5][2]; };

__host__ __device__ __forceinline__ unsigned rotl32(unsigned v, int r) {
  return (v << r) | (v >> (32 - r));
}

__host__ __device__ __forceinline__ void threefry2x32(
    unsigned k0, unsigned k1, unsigned x0, unsigned x1,
    unsigned* o0, unsigned* o1) {
  unsigned ks0 = k0, ks1 = k1, ks2 = k0 ^ k1 ^ 0x1BD11BDAu;
  x0 += ks0; x1 += ks1;
#define TF_RND(r) { x0 += x1; x1 = rotl32(x1, (r)); x1 ^= x0; }
  TF_RND(13) TF_RND(15) TF_RND(26) TF_RND(6)
  x0 += ks1; x1 += ks2 + 1u;
  TF_RND(17) TF_RND(29) TF_RND(16) TF_RND(24)
  x0 += ks2; x1 += ks0 + 2u;
  TF_RND(13) TF_RND(15) TF_RND(26) TF_RND(6)
  x0 += ks0; x1 += ks1 + 3u;
  TF_RND(17) TF_RND(29) TF_RND(16) TF_RND(24)
  x0 += ks1; x1 += ks2 + 4u;
  TF_RND(13) TF_RND(15) TF_RND(26) TF_RND(6)
  x0 += ks2; x1 += ks0 + 5u;
#undef TF_RND
  *o0 = x0; *o1 = x1;
}

__device__ __forceinline__ unsigned short f2bf(float x) {
  unsigned u = __float_as_uint(x);
  unsigned r = (u + 0x7fffu + ((u >> 16) & 1u)) >> 16;
  return (unsigned short)r;
}

// ---------------- walk kernel (unchanged, verified) ----------------
__global__ __launch_bounds__(256) void walk_kernel(
    const int* __restrict__ neighbors, const float* __restrict__ ew,
    const int* __restrict__ target, int* __restrict__ walks, Keys keys) {
  int lane = threadIdx.x & 63;
  int sub = lane & 31;
  int grp = (int)((blockIdx.x * 256 + threadIdx.x) >> 5);
  int wk = grp >= BB ? 1 : 0;
  int b = grp - wk * BB;

  int cur = target[b];
  if (sub == 0) walks[(size_t)grp * 6] = cur;

  const float TINY = 1.17549435e-38f;

  for (int s = 0; s < 5; ++s) {
    int nb = neighbors[(size_t)cur * DEG + sub];
    float w = ew[(size_t)cur * DEG + sub];
    unsigned j = (unsigned)b * DEG + (unsigned)sub;
    unsigned k0 = wk ? keys.l[s][0] : keys.a[s][0];
    unsigned k1 = wk ? keys.l[s][1] : keys.a[s][1];
    unsigned y0, y1;
    threefry2x32(k0, k1, 0u, j, &y0, &y1);
    unsigned bits = y0 ^ y1;
    float f = __uint_as_float((bits >> 9) | 0x3f800000u) - 1.0f;
    float u = fmaxf(TINY, f + TINY);
    float g = -logf(-logf(u));
    float v = g + logf(w);
    int idx = sub;
    #pragma unroll
    for (int off = 16; off; off >>= 1) {
      float vo = __shfl_xor(v, off);
      int io = __shfl_xor(idx, off);
      if (vo > v || (vo == v && io < idx)) { v = vo; idx = io; }
    }
    cur = __shfl(nb, (lane & 32) + idx);
    if (sub == 0) walks[(size_t)grp * 6 + s + 1] = cur;
  }
}

// ---------------- W transpose+bf16 prep: Wt[2][128 n][256 k] ----------------
__global__ __launch_bounds__(256) void prep_w(
    const float* __restrict__ Wapp, const float* __restrict__ Wloc,
    unsigned short* __restrict__ Wt) {
  int blk = blockIdx.x;
  int mat = blk >> 3;
  int k0 = (blk & 7) << 5;
  const float* W = mat ? Wloc : Wapp;
  __shared__ float tile[32][129];
  int t = threadIdx.x;
  #pragma unroll
  for (int i = 0; i < 16; ++i) {
    int idx = t + (i << 8);
    int kk = idx >> 7, n = idx & 127;
    tile[kk][n] = W[((size_t)(k0 + kk) << 7) + n];
  }
  __syncthreads();
  int n = t >> 1, h = (t & 1) << 4;
  unsigned pk[8];
  #pragma unroll
  for (int j = 0; j < 8; ++j) {
    float lo = tile[h + 2 * j][n];
    float hi = tile[h + 2 * j + 1][n];
    pk[j] = (unsigned)f2bf(lo) | ((unsigned)f2bf(hi) << 16);
  }
  unsigned short* dst = Wt + ((size_t)mat << 15) + ((size_t)n << 8) + k0 + h;
  uint4 lo4; lo4.x = pk[0]; lo4.y = pk[1]; lo4.z = pk[2]; lo4.w = pk[3];
  uint4 hi4; hi4.x = pk[4]; hi4.y = pk[5]; hi4.z = pk[6]; hi4.w = pk[7];
  reinterpret_cast<uint4*>(dst)[0] = lo4;
  reinterpret_cast<uint4*>(dst)[1] = hi4;
}

// ---- gather6: walk-shaped gather. One 32-lane group per (side,target). ----
// 24 independent 128-B-granule dword loads per lane; f32 staged output.
// stg[2*BB][256] f32: [target row (128) | walk-sum (128)]; attT[BB] f32.
__global__ void gather6(
    const float* __restrict__ x_app, const float* __restrict__ x_loc,
    const int* __restrict__ walks, const float* __restrict__ W_att,
    float* __restrict__ stg, float* __restrict__ attT) {
  int tid = threadIdx.x;
  int unit = (blockIdx.x << 3) + (tid >> 5);   // [0, 2*BB): side*BB + b
  int l = tid & 31;
  int side = unit >> 14;
  int b = unit & (BB - 1);
  const float* xf = side ? x_loc : x_app;

  int node = 0;
  if (l < 6) node = walks[(size_t)unit * 6 + l];
  int n[6];
  #pragma unroll
  for (int s = 0; s < 6; ++s)
    n[s] = __shfl(node, ((tid & 63) & 32) + s);

  // 24 independent 4-B/lane loads (each instr = 128 B contiguous per group)
  float v[4][6];
  #pragma unroll
  for (int kc = 0; kc < 4; ++kc)
    #pragma unroll
    for (int s = 0; s < 6; ++s)
      v[kc][s] = xf[((size_t)n[s] << 7) + (kc << 5) + l];

  float* row = stg + ((size_t)unit << 8);
  float att = 0.f;
  #pragma unroll
  for (int kc = 0; kc < 4; ++kc) {
    float t0 = v[kc][0];
    float sum = ((((t0 + v[kc][1]) + v[kc][2]) + v[kc][3]) + v[kc][4]) + v[kc][5];
    row[(kc << 5) + l] = t0;
    row[128 + (kc << 5) + l] = sum;
    if (side == 0) att += t0 * W_att[(kc << 5) + l];
  }
  if (side == 0) {
    #pragma unroll
    for (int off = 16; off; off >>= 1) att += __shfl_xor(att, off);
    if (l == 0) attT[b] = att;
  }
}

// ------- gemm6: staged f32 tiles -> bf16 LDS -> MFMA -> attention -------
__global__ void gemm6(
    const float* __restrict__ stg, const float* __restrict__ attT,
    const float* __restrict__ x_time, const int* __restrict__ target,
    const unsigned short* __restrict__ Wt,
    const float* __restrict__ W_att, const float* __restrict__ b_att,
    const float* __restrict__ b_app, const float* __restrict__ b_loc,
    float* __restrict__ out) {
  __shared__ unsigned short sA[BM][264];
  __shared__ unsigned short sL[BM][264];
  __shared__ float4 sRed[4][BM];

  int tid = threadIdx.x;
  int b0 = blockIdx.x * BM;

  // load 16 rows x 2 sides x 256 f32 (coalesced), pack bf16 into LDS
  #pragma unroll
  for (int p = 0; p < 8; ++p) {
    int idx = (p << 8) + tid;            // [0, 2048)
    int side = idx >> 10;
    int row = (idx >> 6) & 15;
    int ch = idx & 63;                   // float4 chunk
    const float4 vv = *(const float4*)&stg[(((size_t)(side * BB + b0 + row)) << 8) + (ch << 2)];
    uint2 pk;
    pk.x = (unsigned)f2bf(vv.x) | ((unsigned)f2bf(vv.y) << 16);
    pk.y = (unsigned)f2bf(vv.z) | ((unsigned)f2bf(vv.w) << 16);
    if (side == 0) *(uint2*)&sA[row][ch << 2] = pk;
    else           *(uint2*)&sL[row][ch << 2] = pk;
  }
  __syncthreads();

  int w = tid >> 6;
  int l = tid & 63;
  int r15 = l & 15, g = l >> 4;

  f32x4 accA[2], accL[2];
  {
    bf16x8 aF[8], lF[8];
    #pragma unroll
    for (int k = 0; k < 8; ++k) {
      aF[k] = *(const bf16x8*)&sA[r15][(k << 5) + (g << 3)];
      lF[k] = *(const bf16x8*)&sL[r15][(k << 5) + (g << 3)];
    }
    #pragma unroll
    for (int n = 0; n < 2; ++n) {
      int col = ((w << 1) + n) << 4;
      f32x4 a1 = {0.f, 0.f, 0.f, 0.f}, a2 = {0.f, 0.f, 0.f, 0.f};
      #pragma unroll
      for (int k = 0; k < 8; ++k) {
        bf16x8 bA = *(const bf16x8*)&Wt[(((size_t)col + r15) << 8) + (k << 5) + (g << 3)];
        bf16x8 bL = *(const bf16x8*)&Wt[(1 << 15) + (((size_t)col + r15) << 8) + (k << 5) + (g << 3)];
        a1 = __builtin_amdgcn_mfma_f32_16x16x32_bf16(aF[k], bA, a1, 0, 0, 0);
        a2 = __builtin_amdgcn_mfma_f32_16x16x32_bf16(lF[k], bL, a2, 0, 0, 0);
      }
      accA[n] = a1;
      accL[n] = a2;
    }
  }

  float bA[2], bL[2], wv[2];
  #pragma unroll
  for (int n = 0; n < 2; ++n) {
    int col = (((w << 1) + n) << 4) + r15;
    bA[n] = b_app[col];
    bL[n] = b_loc[col];
    wv[n] = W_att[128 + col];
  }
  float batt = b_att[0];

  int trow[4];
  #pragma unroll
  for (int r = 0; r < 4; ++r) trow[r] = target[b0 + (g << 2) + r];
  float tts[2][4];
  #pragma unroll
  for (int n = 0; n < 2; ++n)
    #pragma unroll
    for (int r = 0; r < 4; ++r)
      tts[n][r] = x_time[((size_t)trow[r] << 7) + (((w << 1) + n) << 4) + r15];

  float fa[2][4], fl[2][4];
  #pragma unroll
  for (int r = 0; r < 4; ++r) {
    float dA = 0.f, dL = 0.f, dT = 0.f;
    #pragma unroll
    for (int n = 0; n < 2; ++n) {
      fa[n][r] = fmaxf(accA[n][r] + bA[n], 0.f);
      fl[n][r] = fmaxf(accL[n][r] + bL[n], 0.f);
      dA += fa[n][r] * wv[n];
      dL += fl[n][r] * wv[n];
      dT += tts[n][r] * wv[n];
    }
    #pragma unroll
    for (int off = 1; off < 16; off <<= 1) {
      dA += __shfl_xor(dA, off);
      dL += __shfl_xor(dL, off);
      dT += __shfl_xor(dT, off);
    }
    if (r15 == 0) {
      float4 q; q.x = dA; q.y = dL; q.z = dT; q.w = 0.f;
      sRed[w][(g << 2) + r] = q;
    }
  }
  __syncthreads();

  #pragma unroll
  for (int r = 0; r < 4; ++r) {
    int row = (g << 2) + r;
    float4 q0 = sRed[0][row], q1 = sRed[1][row], q2 = sRed[2][row], q3 = sRed[3][row];
    float at = attT[b0 + row] + batt;
    float s0 = at + q0.x + q1.x + q2.x + q3.x;
    float s1 = at + q0.y + q1.y + q2.y + q3.y;
    float s2 = at + q0.z + q1.z + q2.z + q3.z;
    float m = fmaxf(s0, fmaxf(s1, s2));
    float e0 = expf(s0 - m), e1 = expf(s1 - m), e2 = expf(s2 - m);
    float inv = 1.f / (e0 + e1 + e2);
    size_t grow = (size_t)(b0 + row);
    #pragma unroll
    for (int n = 0; n < 2; ++n) {
      int col = (((w << 1) + n) << 4) + r15;
      out[(grow << 7) + col] = (e0 * fa[n][r] + e1 * fl[n][r] + e2 * tts[n][r]) * inv;
    }
  }
}

extern "C" void kernel_launch(void* const* d_in, const int* in_sizes, int n_in,
                              void* d_out, int out_size, void* d_ws, size_t ws_size,
                              hipStream_t stream) {
  (void)in_sizes; (void)n_in; (void)out_size; (void)ws_size;
  const float* x_app   = (const float*)d_in[0];
  const float* x_loc   = (const float*)d_in[1];
  const float* x_time  = (const float*)d_in[2];
  const int*   neighbors = (const int*)d_in[3];
  const float* ew      = (const float*)d_in[4];
  const int*   target  = (const int*)d_in[5];
  const float* W_app   = (const float*)d_in[6];
  const float* b_app   = (const float*)d_in[7];
  const float* W_loc   = (const float*)d_in[8];
  const float* b_loc   = (const float*)d_in[9];
  const float* W_att   = (const float*)d_in[10];
  const float* b_att   = (const float*)d_in[11];
  float* out = (float*)d_out;

  char* ws = (char*)d_ws;
  int* walks = (int*)ws;                                  // 786,432 B
  unsigned short* Wt = (unsigned short*)(ws + 786432);    // 131,072 B
  float* stg = (float*)(ws + 917504);                     // 33,554,432 B
  float* attT = (float*)(ws + 34471936);                  // 65,536 B

  Keys keys;
  unsigned k1a, k1b, k2a, k2b;
  threefry2x32(0u, 42u, 0u, 0u, &k1a, &k1b);
  threefry2x32(0u, 42u, 0u, 1u, &k2a, &k2b);
  for (unsigned s = 0; s < 5; ++s) {
    threefry2x32(k1a, k1b, 0u, s, &keys.a[s][0], &keys.a[s][1]);
    threefry2x32(k2a, k2b, 0u, s, &keys.l[s][0], &keys.l[s][1]);
  }

  walk_kernel<<<(2 * BB * 32) / 256, 256, 0, stream>>>(neighbors, ew, target, walks, keys);
  prep_w<<<16, 256, 0, stream>>>(W_app, W_loc, Wt);
  gather6<<<(2 * BB) / 8, 256, 0, stream>>>(x_app, x_loc, walks, W_att, stg, attT);
  gemm6<<<BB / BM, 256, 0, stream>>>(stg, attT, x_time, target, Wt,
                                     W_att, b_att, b_app, b_loc, out);
}

// Round 8
// 56.638 us; speedup vs baseline: 1.3150x; 1.3150x over previous
//
#include <hip/hip_runtime.h>
#include <stdint.h>

#define NN 200000
#define DEG 32
#define BB 16384
#define DD 128
#define HH 128
#define BM 16

typedef __attribute__((ext_vector_type(8))) short bf16x8;
typedef __attribute__((ext_vector_type(4))) float f32x4;

struct Keys { unsigned a[5][2]; unsigned l[5][2]; };

__host__ __device__ __forceinline__ unsigned rotl32(unsigned v, int r) {
  return (v << r) | (v >> (32 - r));
}

__host__ __device__ __forceinline__ void threefry2x32(
    unsigned k0, unsigned k1, unsigned x0, unsigned x1,
    unsigned* o0, unsigned* o1) {
  unsigned ks0 = k0, ks1 = k1, ks2 = k0 ^ k1 ^ 0x1BD11BDAu;
  x0 += ks0; x1 += ks1;
#define TF_RND(r) { x0 += x1; x1 = rotl32(x1, (r)); x1 ^= x0; }
  TF_RND(13) TF_RND(15) TF_RND(26) TF_RND(6)
  x0 += ks1; x1 += ks2 + 1u;
  TF_RND(17) TF_RND(29) TF_RND(16) TF_RND(24)
  x0 += ks2; x1 += ks0 + 2u;
  TF_RND(13) TF_RND(15) TF_RND(26) TF_RND(6)
  x0 += ks0; x1 += ks1 + 3u;
  TF_RND(17) TF_RND(29) TF_RND(16) TF_RND(24)
  x0 += ks1; x1 += ks2 + 4u;
  TF_RND(13) TF_RND(15) TF_RND(26) TF_RND(6)
  x0 += ks2; x1 += ks0 + 5u;
#undef TF_RND
  *o0 = x0; *o1 = x1;
}

__device__ __forceinline__ unsigned short f2bf(float x) {
  unsigned u = __float_as_uint(x);
  unsigned r = (u + 0x7fffu + ((u >> 16) & 1u)) >> 16;
  return (unsigned short)r;
}

// ---------------- W transpose+bf16 prep: Wt[2][128 n][256 k] ----------------
__global__ __launch_bounds__(256) void prep_w(
    const float* __restrict__ Wapp, const float* __restrict__ Wloc,
    unsigned short* __restrict__ Wt) {
  int blk = blockIdx.x;
  int mat = blk >> 3;
  int k0 = (blk & 7) << 5;
  const float* W = mat ? Wloc : Wapp;
  __shared__ float tile[32][129];
  int t = threadIdx.x;
  #pragma unroll
  for (int i = 0; i < 16; ++i) {
    int idx = t + (i << 8);
    int kk = idx >> 7, n = idx & 127;
    tile[kk][n] = W[((size_t)(k0 + kk) << 7) + n];
  }
  __syncthreads();
  int n = t >> 1, h = (t & 1) << 4;
  unsigned pk[8];
  #pragma unroll
  for (int j = 0; j < 8; ++j) {
    float lo = tile[h + 2 * j][n];
    float hi = tile[h + 2 * j + 1][n];
    pk[j] = (unsigned)f2bf(lo) | ((unsigned)f2bf(hi) << 16);
  }
  unsigned short* dst = Wt + ((size_t)mat << 15) + ((size_t)n << 8) + k0 + h;
  uint4 lo4; lo4.x = pk[0]; lo4.y = pk[1]; lo4.z = pk[2]; lo4.w = pk[3];
  uint4 hi4; hi4.x = pk[4]; hi4.y = pk[5]; hi4.z = pk[6]; hi4.w = pk[7];
  reinterpret_cast<uint4*>(dst)[0] = lo4;
  reinterpret_cast<uint4*>(dst)[1] = hi4;
}

// ---- fully fused: walk -> gather -> MFMA GEMM -> attention, BM=16 ----
__global__ __launch_bounds__(256, 2) void fuse8(
    const float* __restrict__ x_app, const float* __restrict__ x_loc,
    const float* __restrict__ x_time, const int* __restrict__ neighbors,
    const float* __restrict__ ew, const int* __restrict__ target,
    const unsigned short* __restrict__ Wt,
    const float* __restrict__ W_att, const float* __restrict__ b_att,
    const float* __restrict__ b_app, const float* __restrict__ b_loc,
    float* __restrict__ out, Keys keys) {
  __shared__ unsigned short sA[BM][264];
  __shared__ unsigned short sL[BM][264];
  __shared__ float sT[BM][128];
  __shared__ int wn[2][BM][6];
  __shared__ float attT[BM];
  __shared__ float4 sRed[4][BM];

  int tid = threadIdx.x;
  int b0 = blockIdx.x * BM;
  int lane = tid & 63;
  int sub = lane & 31;
  int hw_g = tid >> 5;                     // half-wave 0..7

  const float TINY = 1.17549435e-38f;

  // ---- phase 0: walks in-block (4 units per half-wave; unit = side,t) ----
  for (int u = 0; u < 4; ++u) {
    int unit = (hw_g << 2) + u;            // 0..31
    int side = unit >> 4;
    int t = unit & 15;
    int b = b0 + t;
    int cur = target[b];
    if (sub == 0) wn[side][t][0] = cur;
    for (int s = 0; s < 5; ++s) {
      int nb = neighbors[(size_t)cur * DEG + sub];
      float w = ew[(size_t)cur * DEG + sub];
      unsigned j = (unsigned)b * DEG + (unsigned)sub;
      unsigned k0 = side ? keys.l[s][0] : keys.a[s][0];
      unsigned k1 = side ? keys.l[s][1] : keys.a[s][1];
      unsigned y0, y1;
      threefry2x32(k0, k1, 0u, j, &y0, &y1);
      unsigned bits = y0 ^ y1;
      float f = __uint_as_float((bits >> 9) | 0x3f800000u) - 1.0f;
      float uu = fmaxf(TINY, f + TINY);
      float gg = -logf(-logf(uu));
      float v = gg + logf(w);
      int idx = sub;
      #pragma unroll
      for (int off = 16; off; off >>= 1) {
        float vo = __shfl_xor(v, off);
        int io = __shfl_xor(idx, off);
        if (vo > v || (vo == v && io < idx)) { v = vo; idx = io; }
      }
      cur = __shfl(nb, (lane & 32) + idx);
      if (sub == 0) wn[side][t][s + 1] = cur;
    }
  }
  __syncthreads();

  // ---- phase 1: gather (verified fuse3 pattern + x_time staging) ----
  int c = sub;
  #pragma unroll
  for (int it = 0; it < BM / 8; ++it) {
    int row = (it << 3) + hw_g;
    {
      int n0 = wn[0][row][0], n1 = wn[0][row][1], n2 = wn[0][row][2];
      int n3 = wn[0][row][3], n4 = wn[0][row][4], n5 = wn[0][row][5];
      const float4 v0 = *(const float4*)&x_app[((size_t)n0 << 7) + 4 * c];
      const float4 v1 = *(const float4*)&x_app[((size_t)n1 << 7) + 4 * c];
      const float4 v2 = *(const float4*)&x_app[((size_t)n2 << 7) + 4 * c];
      const float4 v3 = *(const float4*)&x_app[((size_t)n3 << 7) + 4 * c];
      const float4 v4 = *(const float4*)&x_app[((size_t)n4 << 7) + 4 * c];
      const float4 v5 = *(const float4*)&x_app[((size_t)n5 << 7) + 4 * c];
      const float4 tv = *(const float4*)&x_time[((size_t)n0 << 7) + 4 * c];
      float sx = v0.x + v1.x + v2.x + v3.x + v4.x + v5.x;
      float sy = v0.y + v1.y + v2.y + v3.y + v4.y + v5.y;
      float sz = v0.z + v1.z + v2.z + v3.z + v4.z + v5.z;
      float sw = v0.w + v1.w + v2.w + v3.w + v4.w + v5.w;
      uint2 pt, ps;
      pt.x = (unsigned)f2bf(v0.x) | ((unsigned)f2bf(v0.y) << 16);
      pt.y = (unsigned)f2bf(v0.z) | ((unsigned)f2bf(v0.w) << 16);
      ps.x = (unsigned)f2bf(sx) | ((unsigned)f2bf(sy) << 16);
      ps.y = (unsigned)f2bf(sz) | ((unsigned)f2bf(sw) << 16);
      *(uint2*)&sA[row][4 * c] = pt;
      *(uint2*)&sA[row][128 + 4 * c] = ps;
      *(float4*)&sT[row][4 * c] = tv;
      const float4 wa = *(const float4*)&W_att[4 * c];
      float p = v0.x * wa.x + v0.y * wa.y + v0.z * wa.z + v0.w * wa.w;
      #pragma unroll
      for (int off = 16; off; off >>= 1) p += __shfl_xor(p, off);
      if (c == 0) attT[row] = p;
    }
    {
      int n0 = wn[1][row][0], n1 = wn[1][row][1], n2 = wn[1][row][2];
      int n3 = wn[1][row][3], n4 = wn[1][row][4], n5 = wn[1][row][5];
      const float4 v0 = *(const float4*)&x_loc[((size_t)n0 << 7) + 4 * c];
      const float4 v1 = *(const float4*)&x_loc[((size_t)n1 << 7) + 4 * c];
      const float4 v2 = *(const float4*)&x_loc[((size_t)n2 << 7) + 4 * c];
      const float4 v3 = *(const float4*)&x_loc[((size_t)n3 << 7) + 4 * c];
      const float4 v4 = *(const float4*)&x_loc[((size_t)n4 << 7) + 4 * c];
      const float4 v5 = *(const float4*)&x_loc[((size_t)n5 << 7) + 4 * c];
      float sx = v0.x + v1.x + v2.x + v3.x + v4.x + v5.x;
      float sy = v0.y + v1.y + v2.y + v3.y + v4.y + v5.y;
      float sz = v0.z + v1.z + v2.z + v3.z + v4.z + v5.z;
      float sw = v0.w + v1.w + v2.w + v3.w + v4.w + v5.w;
      uint2 pt, ps;
      pt.x = (unsigned)f2bf(v0.x) | ((unsigned)f2bf(v0.y) << 16);
      pt.y = (unsigned)f2bf(v0.z) | ((unsigned)f2bf(v0.w) << 16);
      ps.x = (unsigned)f2bf(sx) | ((unsigned)f2bf(sy) << 16);
      ps.y = (unsigned)f2bf(sz) | ((unsigned)f2bf(sw) << 16);
      *(uint2*)&sL[row][4 * c] = pt;
      *(uint2*)&sL[row][128 + 4 * c] = ps;
    }
  }
  __syncthreads();

  // ---- phase 2: GEMMs (app then loc, sequential to cap VGPR peak) ----
  int w = tid >> 6;
  int l = tid & 63;
  int r15 = l & 15, g = l >> 4;

  f32x4 accA[2], accL[2];
  {
    bf16x8 aF[8];
    #pragma unroll
    for (int k = 0; k < 8; ++k)
      aF[k] = *(const bf16x8*)&sA[r15][(k << 5) + (g << 3)];
    #pragma unroll
    for (int n = 0; n < 2; ++n) {
      size_t colBase = ((size_t)((((w << 1) + n) << 4) + r15)) << 8;
      f32x4 acc = {0.f, 0.f, 0.f, 0.f};
      #pragma unroll
      for (int k = 0; k < 8; ++k) {
        bf16x8 bF = *(const bf16x8*)&Wt[colBase + (k << 5) + (g << 3)];
        acc = __builtin_amdgcn_mfma_f32_16x16x32_bf16(aF[k], bF, acc, 0, 0, 0);
      }
      accA[n] = acc;
    }
  }
  {
    bf16x8 lF[8];
    #pragma unroll
    for (int k = 0; k < 8; ++k)
      lF[k] = *(const bf16x8*)&sL[r15][(k << 5) + (g << 3)];
    const unsigned short* WtL = Wt + (1 << 15);
    #pragma unroll
    for (int n = 0; n < 2; ++n) {
      size_t colBase = ((size_t)((((w << 1) + n) << 4) + r15)) << 8;
      f32x4 acc = {0.f, 0.f, 0.f, 0.f};
      #pragma unroll
      for (int k = 0; k < 8; ++k) {
        bf16x8 bF = *(const bf16x8*)&WtL[colBase + (k << 5) + (g << 3)];
        acc = __builtin_amdgcn_mfma_f32_16x16x32_bf16(lF[k], bF, acc, 0, 0, 0);
      }
      accL[n] = acc;
    }
  }

  // ---- phase 3: attention epilogue (x_time from LDS) ----
  float bA[2], bL[2], wv[2];
  #pragma unroll
  for (int n = 0; n < 2; ++n) {
    int col = (((w << 1) + n) << 4) + r15;
    bA[n] = b_app[col];
    bL[n] = b_loc[col];
    wv[n] = W_att[128 + col];
  }
  float batt = b_att[0];

  float tts[2][4];
  #pragma unroll
  for (int n = 0; n < 2; ++n)
    #pragma unroll
    for (int r = 0; r < 4; ++r)
      tts[n][r] = sT[(g << 2) + r][(((w << 1) + n) << 4) + r15];

  float fa[2][4], fl[2][4];
  #pragma unroll
  for (int r = 0; r < 4; ++r) {
    float dA = 0.f, dL = 0.f, dT = 0.f;
    #pragma unroll
    for (int n = 0; n < 2; ++n) {
      fa[n][r] = fmaxf(accA[n][r] + bA[n], 0.f);
      fl[n][r] = fmaxf(accL[n][r] + bL[n], 0.f);
      dA += fa[n][r] * wv[n];
      dL += fl[n][r] * wv[n];
      dT += tts[n][r] * wv[n];
    }
    #pragma unroll
    for (int off = 1; off < 16; off <<= 1) {
      dA += __shfl_xor(dA, off);
      dL += __shfl_xor(dL, off);
      dT += __shfl_xor(dT, off);
    }
    if (r15 == 0) {
      float4 q; q.x = dA; q.y = dL; q.z = dT; q.w = 0.f;
      sRed[w][(g << 2) + r] = q;
    }
  }
  __syncthreads();

  #pragma unroll
  for (int r = 0; r < 4; ++r) {
    int row = (g << 2) + r;
    float4 q0 = sRed[0][row], q1 = sRed[1][row], q2 = sRed[2][row], q3 = sRed[3][row];
    float at = attT[row] + batt;
    float s0 = at + q0.x + q1.x + q2.x + q3.x;
    float s1 = at + q0.y + q1.y + q2.y + q3.y;
    float s2 = at + q0.z + q1.z + q2.z + q3.z;
    float m = fmaxf(s0, fmaxf(s1, s2));
    float e0 = expf(s0 - m), e1 = expf(s1 - m), e2 = expf(s2 - m);
    float inv = 1.f / (e0 + e1 + e2);
    size_t grow = (size_t)(b0 + row);
    #pragma unroll
    for (int n = 0; n < 2; ++n) {
      int col = (((w << 1) + n) << 4) + r15;
      out[(grow << 7) + col] = (e0 * fa[n][r] + e1 * fl[n][r] + e2 * tts[n][r]) * inv;
    }
  }
}

extern "C" void kernel_launch(void* const* d_in, const int* in_sizes, int n_in,
                              void* d_out, int out_size, void* d_ws, size_t ws_size,
                              hipStream_t stream) {
  (void)in_sizes; (void)n_in; (void)out_size; (void)ws_size;
  const float* x_app   = (const float*)d_in[0];
  const float* x_loc   = (const float*)d_in[1];
  const float* x_time  = (const float*)d_in[2];
  const int*   neighbors = (const int*)d_in[3];
  const float* ew      = (const float*)d_in[4];
  const int*   target  = (const int*)d_in[5];
  const float* W_app   = (const float*)d_in[6];
  const float* b_app   = (const float*)d_in[7];
  const float* W_loc   = (const float*)d_in[8];
  const float* b_loc   = (const float*)d_in[9];
  const float* W_att   = (const float*)d_in[10];
  const float* b_att   = (const float*)d_in[11];
  float* out = (float*)d_out;
  unsigned short* Wt = (unsigned short*)d_ws;   // 128 KB

  Keys keys;
  unsigned k1a, k1b, k2a, k2b;
  threefry2x32(0u, 42u, 0u, 0u, &k1a, &k1b);
  threefry2x32(0u, 42u, 0u, 1u, &k2a, &k2b);
  for (unsigned s = 0; s < 5; ++s) {
    threefry2x32(k1a, k1b, 0u, s, &keys.a[s][0], &keys.a[s][1]);
    threefry2x32(k2a, k2b, 0u, s, &keys.l[s][0], &keys.l[s][1]);
  }

  prep_w<<<16, 256, 0, stream>>>(W_app, W_loc, Wt);
  fuse8<<<BB / BM, 256, 0, stream>>>(x_app, x_loc, x_time, neighbors, ew,
                                     target, Wt, W_att, b_att, b_app, b_loc,
                                     out, keys);
}

// Round 9
// 52.404 us; speedup vs baseline: 1.4213x; 1.0808x over previous
//
#include <hip/hip_runtime.h>
#include <stdint.h>

#define NN 200000
#define DEG 32
#define BB 16384
#define DD 128
#define HH 128
#define BM 16

typedef __attribute__((ext_vector_type(8))) short bf16x8;
typedef __attribute__((ext_vector_type(4))) float f32x4;

struct Keys { unsigned a[5][2]; unsigned l[5][2]; };

__host__ __device__ __forceinline__ unsigned rotl32(unsigned v, int r) {
  return (v << r) | (v >> (32 - r));
}

__host__ __device__ __forceinline__ void threefry2x32(
    unsigned k0, unsigned k1, unsigned x0, unsigned x1,
    unsigned* o0, unsigned* o1) {
  unsigned ks0 = k0, ks1 = k1, ks2 = k0 ^ k1 ^ 0x1BD11BDAu;
  x0 += ks0; x1 += ks1;
#define TF_RND(r) { x0 += x1; x1 = rotl32(x1, (r)); x1 ^= x0; }
  TF_RND(13) TF_RND(15) TF_RND(26) TF_RND(6)
  x0 += ks1; x1 += ks2 + 1u;
  TF_RND(17) TF_RND(29) TF_RND(16) TF_RND(24)
  x0 += ks2; x1 += ks0 + 2u;
  TF_RND(13) TF_RND(15) TF_RND(26) TF_RND(6)
  x0 += ks0; x1 += ks1 + 3u;
  TF_RND(17) TF_RND(29) TF_RND(16) TF_RND(24)
  x0 += ks1; x1 += ks2 + 4u;
  TF_RND(13) TF_RND(15) TF_RND(26) TF_RND(6)
  x0 += ks2; x1 += ks0 + 5u;
#undef TF_RND
  *o0 = x0; *o1 = x1;
}

__device__ __forceinline__ unsigned short f2bf(float x) {
  unsigned u = __float_as_uint(x);
  unsigned r = (u + 0x7fffu + ((u >> 16) & 1u)) >> 16;
  return (unsigned short)r;
}

// ---------------- W transpose+bf16 prep: Wt[2][128 n][256 k] ----------------
__global__ __launch_bounds__(256) void prep_w(
    const float* __restrict__ Wapp, const float* __restrict__ Wloc,
    unsigned short* __restrict__ Wt) {
  int blk = blockIdx.x;
  int mat = blk >> 3;
  int k0 = (blk & 7) << 5;
  const float* W = mat ? Wloc : Wapp;
  __shared__ float tile[32][129];
  int t = threadIdx.x;
  #pragma unroll
  for (int i = 0; i < 16; ++i) {
    int idx = t + (i << 8);
    int kk = idx >> 7, n = idx & 127;
    tile[kk][n] = W[((size_t)(k0 + kk) << 7) + n];
  }
  __syncthreads();
  int n = t >> 1, h = (t & 1) << 4;
  unsigned pk[8];
  #pragma unroll
  for (int j = 0; j < 8; ++j) {
    float lo = tile[h + 2 * j][n];
    float hi = tile[h + 2 * j + 1][n];
    pk[j] = (unsigned)f2bf(lo) | ((unsigned)f2bf(hi) << 16);
  }
  unsigned short* dst = Wt + ((size_t)mat << 15) + ((size_t)n << 8) + k0 + h;
  uint4 lo4; lo4.x = pk[0]; lo4.y = pk[1]; lo4.z = pk[2]; lo4.w = pk[3];
  uint4 hi4; hi4.x = pk[4]; hi4.y = pk[5]; hi4.z = pk[6]; hi4.w = pk[7];
  reinterpret_cast<uint4*>(dst)[0] = lo4;
  reinterpret_cast<uint4*>(dst)[1] = hi4;
}

// ---- fully fused: interleaved walks -> gather -> MFMA GEMM -> attention ----
__global__ __launch_bounds__(256, 2) void fuse9(
    const float* __restrict__ x_app, const float* __restrict__ x_loc,
    const float* __restrict__ x_time, const int* __restrict__ neighbors,
    const float* __restrict__ ew, const int* __restrict__ target,
    const unsigned short* __restrict__ Wt,
    const float* __restrict__ W_att, const float* __restrict__ b_att,
    const float* __restrict__ b_app, const float* __restrict__ b_loc,
    float* __restrict__ out, Keys keys) {
  __shared__ unsigned short sA[BM][264];
  __shared__ unsigned short sL[BM][264];
  __shared__ float sT[BM][128];
  __shared__ int wn[2][BM][6];
  __shared__ float attT[BM];
  __shared__ float4 sRed[4][BM];

  int tid = threadIdx.x;
  int b0 = blockIdx.x * BM;
  int lane = tid & 63;
  int sub = lane & 31;
  int hw_g = tid >> 5;                     // half-wave 0..7

  const float TINY = 1.17549435e-38f;

  // ---- phase 0: walks — 4 INDEPENDENT unit-chains interleaved ----
  // unit = (hw_g<<2)+u in [0,32): side = unit>>4, t = unit&15
  int cur[4];
  #pragma unroll
  for (int u = 0; u < 4; ++u) {
    int unit = (hw_g << 2) + u;
    int side = unit >> 4, t = unit & 15;
    cur[u] = target[b0 + t];
    if (sub == 0) wn[side][t][0] = cur[u];
  }
  for (int s = 0; s < 5; ++s) {
    int nb[4]; float wgt[4];
    #pragma unroll
    for (int u = 0; u < 4; ++u) {
      nb[u] = neighbors[(size_t)cur[u] * DEG + sub];
      wgt[u] = ew[(size_t)cur[u] * DEG + sub];
    }
    #pragma unroll
    for (int u = 0; u < 4; ++u) {
      int unit = (hw_g << 2) + u;
      int side = unit >> 4, t = unit & 15;
      unsigned j = (unsigned)(b0 + t) * DEG + (unsigned)sub;
      unsigned k0 = side ? keys.l[s][0] : keys.a[s][0];
      unsigned k1 = side ? keys.l[s][1] : keys.a[s][1];
      unsigned y0, y1;
      threefry2x32(k0, k1, 0u, j, &y0, &y1);
      unsigned bits = y0 ^ y1;
      float f = __uint_as_float((bits >> 9) | 0x3f800000u) - 1.0f;
      float uu = fmaxf(TINY, f + TINY);
      float gg = -logf(-logf(uu));
      float v = gg + logf(wgt[u]);
      int idx = sub;
      #pragma unroll
      for (int off = 16; off; off >>= 1) {
        float vo = __shfl_xor(v, off);
        int io = __shfl_xor(idx, off);
        if (vo > v || (vo == v && io < idx)) { v = vo; idx = io; }
      }
      cur[u] = __shfl(nb[u], (lane & 32) + idx);
      if (sub == 0) wn[side][t][s + 1] = cur[u];
    }
  }
  __syncthreads();

  // ---- phase 1: gather (verified pattern + x_time staging) ----
  int c = sub;
  #pragma unroll
  for (int it = 0; it < BM / 8; ++it) {
    int row = (it << 3) + hw_g;
    {
      int n0 = wn[0][row][0], n1 = wn[0][row][1], n2 = wn[0][row][2];
      int n3 = wn[0][row][3], n4 = wn[0][row][4], n5 = wn[0][row][5];
      const float4 v0 = *(const float4*)&x_app[((size_t)n0 << 7) + 4 * c];
      const float4 v1 = *(const float4*)&x_app[((size_t)n1 << 7) + 4 * c];
      const float4 v2 = *(const float4*)&x_app[((size_t)n2 << 7) + 4 * c];
      const float4 v3 = *(const float4*)&x_app[((size_t)n3 << 7) + 4 * c];
      const float4 v4 = *(const float4*)&x_app[((size_t)n4 << 7) + 4 * c];
      const float4 v5 = *(const float4*)&x_app[((size_t)n5 << 7) + 4 * c];
      const float4 tv = *(const float4*)&x_time[((size_t)n0 << 7) + 4 * c];
      float sx = v0.x + v1.x + v2.x + v3.x + v4.x + v5.x;
      float sy = v0.y + v1.y + v2.y + v3.y + v4.y + v5.y;
      float sz = v0.z + v1.z + v2.z + v3.z + v4.z + v5.z;
      float sw = v0.w + v1.w + v2.w + v3.w + v4.w + v5.w;
      uint2 pt, ps;
      pt.x = (unsigned)f2bf(v0.x) | ((unsigned)f2bf(v0.y) << 16);
      pt.y = (unsigned)f2bf(v0.z) | ((unsigned)f2bf(v0.w) << 16);
      ps.x = (unsigned)f2bf(sx) | ((unsigned)f2bf(sy) << 16);
      ps.y = (unsigned)f2bf(sz) | ((unsigned)f2bf(sw) << 16);
      *(uint2*)&sA[row][4 * c] = pt;
      *(uint2*)&sA[row][128 + 4 * c] = ps;
      *(float4*)&sT[row][4 * c] = tv;
      const float4 wa = *(const float4*)&W_att[4 * c];
      float p = v0.x * wa.x + v0.y * wa.y + v0.z * wa.z + v0.w * wa.w;
      #pragma unroll
      for (int off = 16; off; off >>= 1) p += __shfl_xor(p, off);
      if (c == 0) attT[row] = p;
    }
    {
      int n0 = wn[1][row][0], n1 = wn[1][row][1], n2 = wn[1][row][2];
      int n3 = wn[1][row][3], n4 = wn[1][row][4], n5 = wn[1][row][5];
      const float4 v0 = *(const float4*)&x_loc[((size_t)n0 << 7) + 4 * c];
      const float4 v1 = *(const float4*)&x_loc[((size_t)n1 << 7) + 4 * c];
      const float4 v2 = *(const float4*)&x_loc[((size_t)n2 << 7) + 4 * c];
      const float4 v3 = *(const float4*)&x_loc[((size_t)n3 << 7) + 4 * c];
      const float4 v4 = *(const float4*)&x_loc[((size_t)n4 << 7) + 4 * c];
      const float4 v5 = *(const float4*)&x_loc[((size_t)n5 << 7) + 4 * c];
      float sx = v0.x + v1.x + v2.x + v3.x + v4.x + v5.x;
      float sy = v0.y + v1.y + v2.y + v3.y + v4.y + v5.y;
      float sz = v0.z + v1.z + v2.z + v3.z + v4.z + v5.z;
      float sw = v0.w + v1.w + v2.w + v3.w + v4.w + v5.w;
      uint2 pt, ps;
      pt.x = (unsigned)f2bf(v0.x) | ((unsigned)f2bf(v0.y) << 16);
      pt.y = (unsigned)f2bf(v0.z) | ((unsigned)f2bf(v0.w) << 16);
      ps.x = (unsigned)f2bf(sx) | ((unsigned)f2bf(sy) << 16);
      ps.y = (unsigned)f2bf(sz) | ((unsigned)f2bf(sw) << 16);
      *(uint2*)&sL[row][4 * c] = pt;
      *(uint2*)&sL[row][128 + 4 * c] = ps;
    }
  }
  __syncthreads();

  // ---- phase 2: GEMMs (app then loc, sequential to cap VGPR peak) ----
  int w = tid >> 6;
  int l = tid & 63;
  int r15 = l & 15, g = l >> 4;

  f32x4 accA[2], accL[2];
  {
    bf16x8 aF[8];
    #pragma unroll
    for (int k = 0; k < 8; ++k)
      aF[k] = *(const bf16x8*)&sA[r15][(k << 5) + (g << 3)];
    #pragma unroll
    for (int n = 0; n < 2; ++n) {
      size_t colBase = ((size_t)((((w << 1) + n) << 4) + r15)) << 8;
      f32x4 acc = {0.f, 0.f, 0.f, 0.f};
      #pragma unroll
      for (int k = 0; k < 8; ++k) {
        bf16x8 bF = *(const bf16x8*)&Wt[colBase + (k << 5) + (g << 3)];
        acc = __builtin_amdgcn_mfma_f32_16x16x32_bf16(aF[k], bF, acc, 0, 0, 0);
      }
      accA[n] = acc;
    }
  }
  {
    bf16x8 lF[8];
    #pragma unroll
    for (int k = 0; k < 8; ++k)
      lF[k] = *(const bf16x8*)&sL[r15][(k << 5) + (g << 3)];
    const unsigned short* WtL = Wt + (1 << 15);
    #pragma unroll
    for (int n = 0; n < 2; ++n) {
      size_t colBase = ((size_t)((((w << 1) + n) << 4) + r15)) << 8;
      f32x4 acc = {0.f, 0.f, 0.f, 0.f};
      #pragma unroll
      for (int k = 0; k < 8; ++k) {
        bf16x8 bF = *(const bf16x8*)&WtL[colBase + (k << 5) + (g << 3)];
        acc = __builtin_amdgcn_mfma_f32_16x16x32_bf16(lF[k], bF, acc, 0, 0, 0);
      }
      accL[n] = acc;
    }
  }

  // ---- phase 3: attention epilogue (x_time from LDS) ----
  float bA[2], bL[2], wv[2];
  #pragma unroll
  for (int n = 0; n < 2; ++n) {
    int col = (((w << 1) + n) << 4) + r15;
    bA[n] = b_app[col];
    bL[n] = b_loc[col];
    wv[n] = W_att[128 + col];
  }
  float batt = b_att[0];

  float tts[2][4];
  #pragma unroll
  for (int n = 0; n < 2; ++n)
    #pragma unroll
    for (int r = 0; r < 4; ++r)
      tts[n][r] = sT[(g << 2) + r][(((w << 1) + n) << 4) + r15];

  float fa[2][4], fl[2][4];
  #pragma unroll
  for (int r = 0; r < 4; ++r) {
    float dA = 0.f, dL = 0.f, dT = 0.f;
    #pragma unroll
    for (int n = 0; n < 2; ++n) {
      fa[n][r] = fmaxf(accA[n][r] + bA[n], 0.f);
      fl[n][r] = fmaxf(accL[n][r] + bL[n], 0.f);
      dA += fa[n][r] * wv[n];
      dL += fl[n][r] * wv[n];
      dT += tts[n][r] * wv[n];
    }
    #pragma unroll
    for (int off = 1; off < 16; off <<= 1) {
      dA += __shfl_xor(dA, off);
      dL += __shfl_xor(dL, off);
      dT += __shfl_xor(dT, off);
    }
    if (r15 == 0) {
      float4 q; q.x = dA; q.y = dL; q.z = dT; q.w = 0.f;
      sRed[w][(g << 2) + r] = q;
    }
  }
  __syncthreads();

  #pragma unroll
  for (int r = 0; r < 4; ++r) {
    int row = (g << 2) + r;
    float4 q0 = sRed[0][row], q1 = sRed[1][row], q2 = sRed[2][row], q3 = sRed[3][row];
    float at = attT[row] + batt;
    float s0 = at + q0.x + q1.x + q2.x + q3.x;
    float s1 = at + q0.y + q1.y + q2.y + q3.y;
    float s2 = at + q0.z + q1.z + q2.z + q3.z;
    float m = fmaxf(s0, fmaxf(s1, s2));
    float e0 = expf(s0 - m), e1 = expf(s1 - m), e2 = expf(s2 - m);
    float inv = 1.f / (e0 + e1 + e2);
    size_t grow = (size_t)(b0 + row);
    #pragma unroll
    for (int n = 0; n < 2; ++n) {
      int col = (((w << 1) + n) << 4) + r15;
      out[(grow << 7) + col] = (e0 * fa[n][r] + e1 * fl[n][r] + e2 * tts[n][r]) * inv;
    }
  }
}

extern "C" void kernel_launch(void* const* d_in, const int* in_sizes, int n_in,
                              void* d_out, int out_size, void* d_ws, size_t ws_size,
                              hipStream_t stream) {
  (void)in_sizes; (void)n_in; (void)out_size; (void)ws_size;
  const float* x_app   = (const float*)d_in[0];
  const float* x_loc   = (const float*)d_in[1];
  const float* x_time  = (const float*)d_in[2];
  const int*   neighbors = (const int*)d_in[3];
  const float* ew      = (const float*)d_in[4];
  const int*   target  = (const int*)d_in[5];
  const float* W_app   = (const float*)d_in[6];
  const float* b_app   = (const float*)d_in[7];
  const float* W_loc   = (const float*)d_in[8];
  const float* b_loc   = (const float*)d_in[9];
  const float* W_att   = (const float*)d_in[10];
  const float* b_att   = (const float*)d_in[11];
  float* out = (float*)d_out;
  unsigned short* Wt = (unsigned short*)d_ws;   // 128 KB

  Keys keys;
  unsigned k1a, k1b, k2a, k2b;
  threefry2x32(0u, 42u, 0u, 0u, &k1a, &k1b);
  threefry2x32(0u, 42u, 0u, 1u, &k2a, &k2b);
  for (unsigned s = 0; s < 5; ++s) {
    threefry2x32(k1a, k1b, 0u, s, &keys.a[s][0], &keys.a[s][1]);
    threefry2x32(k2a, k2b, 0u, s, &keys.l[s][0], &keys.l[s][1]);
  }

  prep_w<<<16, 256, 0, stream>>>(W_app, W_loc, Wt);
  fuse9<<<BB / BM, 256, 0, stream>>>(x_app, x_loc, x_time, neighbors, ew,
                                     target, Wt, W_att, b_att, b_app, b_loc,
                                     out, keys);
}